// Round 3
// baseline (1246.830 us; speedup 1.0000x reference)
//
#include <hip/hip_runtime.h>
#include <hip/hip_bf16.h>
#include <math.h>

#define NT 16384
#define DM 1024
#define NE 4

typedef __attribute__((ext_vector_type(8))) short short8;  // 8 bf16 (4 VGPRs)
typedef __attribute__((ext_vector_type(4))) float f32x4;

// ============ dtype detection: bf16 vs fp32, from bit statistics of x ========
// Word bits 14..7: bf16-pair -> element0 exponent (sane for N(0,1) data);
// fp32 -> mantissa bits (uniform). Count sane in first 16384 words.
__global__ __launch_bounds__(256) void detect_kernel(
    const unsigned int* __restrict__ xw, int* __restrict__ flag)
{
    __shared__ int red[4];
    const int t = threadIdx.x;
    int cnt = 0;
    #pragma unroll 4
    for (int i = 0; i < 64; ++i) {
        unsigned w = xw[t * 64 + i];
        unsigned e0 = (w >> 7) & 0xFFu;
        cnt += (e0 >= 100u && e0 <= 150u) ? 1 : 0;
    }
    #pragma unroll
    for (int o = 32; o > 0; o >>= 1) cnt += __shfl_xor(cnt, o);
    if ((t & 63) == 0) red[t >> 6] = cnt;
    __syncthreads();
    if (t == 0) {
        int tot = red[0] + red[1] + red[2] + red[3];
        *flag = (tot > 8192) ? 1 : 0;   // 1 = bf16 inputs, 0 = fp32 inputs
    }
}

// ============ convert input -> bf16 ws buffer (copy if already bf16) =========
__global__ __launch_bounds__(256) void convert_kernel(
    const void* __restrict__ src, short* __restrict__ dst, int n,
    const int* __restrict__ flag)
{
    const int stride = gridDim.x * blockDim.x;
    const int t0 = blockIdx.x * blockDim.x + threadIdx.x;
    if (*flag) {
        const int4* s = (const int4*)src;
        int4* d = (int4*)dst;
        for (int i = t0; i < n / 8; i += stride) d[i] = s[i];
    } else {
        const float4* s = (const float4*)src;
        for (int i = t0; i < n / 4; i += stride) {
            float4 v = s[i];
            __hip_bfloat16 b0 = __float2bfloat16(v.x);
            __hip_bfloat16 b1 = __float2bfloat16(v.y);
            __hip_bfloat16 b2 = __float2bfloat16(v.z);
            __hip_bfloat16 b3 = __float2bfloat16(v.w);
            short4 o;
            o.x = *(short*)&b0; o.y = *(short*)&b1;
            o.z = *(short*)&b2; o.w = *(short*)&b3;
            *(short4*)(dst + (size_t)i * 4) = o;
        }
    }
}

// ============ gate: RAW inputs (exact routing), fp64 acc -> comb[NT,4] =======
__global__ __launch_bounds__(256) void gate_kernel(
    const void* __restrict__ x, const void* __restrict__ gw,
    float* __restrict__ comb, const int* __restrict__ flag)
{
    const int isbf = *flag;
    const int lane  = threadIdx.x & 63;
    const int token = blockIdx.x * 4 + (threadIdx.x >> 6);
    double s0 = 0., s1 = 0., s2 = 0., s3 = 0.;
    for (int c = 0; c < DM; c += 64) {
        const size_t xi = (size_t)token * DM + c + lane;
        const size_t gi = c + lane;
        double xv, g0, g1, g2, g3;
        if (isbf) {
            xv = (double)__bfloat162float(((const __hip_bfloat16*)x)[xi]);
            g0 = (double)__bfloat162float(((const __hip_bfloat16*)gw)[0 * DM + gi]);
            g1 = (double)__bfloat162float(((const __hip_bfloat16*)gw)[1 * DM + gi]);
            g2 = (double)__bfloat162float(((const __hip_bfloat16*)gw)[2 * DM + gi]);
            g3 = (double)__bfloat162float(((const __hip_bfloat16*)gw)[3 * DM + gi]);
        } else {
            xv = (double)((const float*)x)[xi];
            g0 = (double)((const float*)gw)[0 * DM + gi];
            g1 = (double)((const float*)gw)[1 * DM + gi];
            g2 = (double)((const float*)gw)[2 * DM + gi];
            g3 = (double)((const float*)gw)[3 * DM + gi];
        }
        s0 += xv * g0; s1 += xv * g1; s2 += xv * g2; s3 += xv * g3;
    }
    #pragma unroll
    for (int off = 32; off > 0; off >>= 1) {
        s0 += __shfl_xor(s0, off);
        s1 += __shfl_xor(s1, off);
        s2 += __shfl_xor(s2, off);
        s3 += __shfl_xor(s3, off);
    }
    if (lane == 0) {
        double s[4] = {s0, s1, s2, s3};
        int i1 = 0;
        #pragma unroll
        for (int e = 1; e < 4; ++e) if (s[e] > s[i1]) i1 = e;  // ties -> lowest idx
        int i2 = -1;
        #pragma unroll
        for (int e = 0; e < 4; ++e) {
            if (e == i1) continue;
            if (i2 < 0 || s[e] > s[i2]) i2 = e;
        }
        float e2 = expf((float)(s[i2] - s[i1]));   // <= 1, stable
        float wa = 1.0f / (1.0f + e2);
        float wb = e2 * wa;
        float* cr = comb + (size_t)token * 4;
        #pragma unroll
        for (int e = 0; e < 4; ++e)
            cr[e] = (e == i1) ? wa : ((e == i2) ? wb : 0.0f);
    }
}

// ---------------- GEMM: C[M,N] = A[M,K] @ B[N,K]^T (both K-contiguous bf16) ----
// EPI 0: out bf16 = gelu_exact(acc + bias[col])              (h = gelu(x@w1^T+b1))
// EPI 1: out f32  = acc + bias[col] + bf16 xres[row*N+col]   (z = x + h@w2^T+b2)
template <int EPI>
__global__ __launch_bounds__(256, 2) void gemm_bt(
    const short* __restrict__ A,               // [M,K] bf16 bits
    const short* __restrict__ B,               // [N,K] bf16 bits
    const __hip_bfloat16* __restrict__ bias,   // [N]
    const __hip_bfloat16* __restrict__ xres,   // [M,N] (EPI==1)
    void* __restrict__ Cout,
    int M, int N, int K)
{
    __shared__ __align__(16) short sA[128 * 64];
    __shared__ __align__(16) short sB[128 * 64];
    const int tid  = threadIdx.x;
    const int wid  = tid >> 6;
    const int lane = tid & 63;
    const int row0 = blockIdx.y * 128;
    const int col0 = blockIdx.x * 128;
    const int wm = wid >> 1, wn = wid & 1;     // 2x2 waves, 64x64 each
    const int srow = tid >> 3;                 // staging: 32 rows / pass
    const int scol = (tid & 7) * 8;            // 8 bf16 per thread per row
    const int quad = lane >> 4;
    const int mrow = lane & 15;

    f32x4 acc[4][4];
    #pragma unroll
    for (int i = 0; i < 4; ++i)
        #pragma unroll
        for (int j = 0; j < 4; ++j)
            acc[i][j] = (f32x4){0.f, 0.f, 0.f, 0.f};

    for (int k0 = 0; k0 < K; k0 += 64) {
        short8 av[4], bv[4];
        #pragma unroll
        for (int r = 0; r < 4; ++r) {
            const int row = r * 32 + srow;
            av[r] = *(const short8*)(A + (size_t)(row0 + row) * K + k0 + scol);
            bv[r] = *(const short8*)(B + (size_t)(col0 + row) * K + k0 + scol);
        }
        __syncthreads();   // all waves done reading LDS of previous iteration
        #pragma unroll
        for (int r = 0; r < 4; ++r) {
            const int row = r * 32 + srow;
            *(short8*)(sA + row * 64 + scol) = av[r];
            *(short8*)(sB + row * 64 + scol) = bv[r];
        }
        __syncthreads();
        #pragma unroll
        for (int kk = 0; kk < 64; kk += 32) {
            short8 a[4], b[4];
            #pragma unroll
            for (int t = 0; t < 4; ++t) {
                a[t] = *(const short8*)(sA + (wm * 64 + t * 16 + mrow) * 64 + kk + quad * 8);
                b[t] = *(const short8*)(sB + (wn * 64 + t * 16 + mrow) * 64 + kk + quad * 8);
            }
            #pragma unroll
            for (int mt = 0; mt < 4; ++mt)
                #pragma unroll
                for (int nt = 0; nt < 4; ++nt)
                    acc[mt][nt] = __builtin_amdgcn_mfma_f32_16x16x32_bf16(
                        a[mt], b[nt], acc[mt][nt], 0, 0, 0);
        }
    }

    // epilogue: C/D layout col=lane&15, row=quad*4+reg (m89-verified)
    #pragma unroll
    for (int mt = 0; mt < 4; ++mt) {
        #pragma unroll
        for (int nt = 0; nt < 4; ++nt) {
            const int col = col0 + wn * 64 + nt * 16 + mrow;
            const float bval = __bfloat162float(bias[col]);
            #pragma unroll
            for (int i = 0; i < 4; ++i) {
                const int row = row0 + wm * 64 + mt * 16 + quad * 4 + i;
                float v = acc[mt][nt][i] + bval;
                if (EPI == 0) {
                    v = 0.5f * v * (1.0f + erff(v * 0.70710678118654752f));
                    ((__hip_bfloat16*)Cout)[(size_t)row * N + col] = __float2bfloat16(v);
                } else {
                    v += __bfloat162float(xres[(size_t)row * N + col]);
                    ((float*)Cout)[(size_t)row * N + col] = v;
                }
            }
        }
    }
}

// ---------------- LN + gate-weighted accumulate into y (dtype per flag) ------
__global__ __launch_bounds__(256) void ln_kernel(
    const float* __restrict__ z,               // [Mc, DM] fp32 (chunk)
    const float* __restrict__ comb,            // [NT, 4]
    const __hip_bfloat16* __restrict__ gamma,  // [DM] (expert slice)
    const __hip_bfloat16* __restrict__ beta,   // [DM]
    void* __restrict__ y,                      // [NT, DM] bf16 or fp32
    int expert, int accumulate, int chunk_start,
    const int* __restrict__ flag)
{
    const int isbf  = *flag;
    const int lane  = threadIdx.x & 63;
    const int tloc  = blockIdx.x * 4 + (threadIdx.x >> 6);
    const int token = chunk_start + tloc;
    const f32x4* zr = (const f32x4*)(z + (size_t)tloc * DM);
    f32x4 v[4];
    float sum = 0.f, ssq = 0.f;
    #pragma unroll
    for (int c = 0; c < 4; ++c) {
        v[c] = zr[c * 64 + lane];
        #pragma unroll
        for (int j = 0; j < 4; ++j) { sum += v[c][j]; ssq += v[c][j] * v[c][j]; }
    }
    #pragma unroll
    for (int off = 32; off > 0; off >>= 1) {
        sum += __shfl_xor(sum, off);
        ssq += __shfl_xor(ssq, off);
    }
    const float mu   = sum * (1.0f / DM);
    const float var  = fmaxf(ssq * (1.0f / DM) - mu * mu, 0.0f);
    const float rstd = rsqrtf(var + 1e-6f);
    const float w    = comb[(size_t)token * 4 + expert];
    #pragma unroll
    for (int c = 0; c < 4; ++c) {
        #pragma unroll
        for (int j = 0; j < 4; ++j) {
            const int idx = c * 256 + lane * 4 + j;
            const float g = __bfloat162float(gamma[idx]);
            const float b = __bfloat162float(beta[idx]);
            float o = w * ((v[c][j] - mu) * rstd * g + b);
            if (isbf) {
                __hip_bfloat16* yr = (__hip_bfloat16*)y + (size_t)token * DM;
                if (accumulate) o += __bfloat162float(yr[idx]);
                yr[idx] = __float2bfloat16(o);
            } else {
                float* yr = (float*)y + (size_t)token * DM;
                if (accumulate) o += yr[idx];
                yr[idx] = o;
            }
        }
    }
}

extern "C" void kernel_launch(void* const* d_in, const int* in_sizes, int n_in,
                              void* d_out, int out_size, void* d_ws, size_t ws_size,
                              hipStream_t stream)
{
    char* ws = (char*)d_ws;
    size_t off = 0;
    auto alloc = [&](size_t bytes) -> char* {
        char* p = ws + off;
        off = (off + bytes + 255) & ~(size_t)255;
        return p;
    };
    int*   flag = (int*)  alloc(256);
    float* comb = (float*)alloc((size_t)NT * 4 * sizeof(float));
    short* gwb  = (short*)alloc((size_t)NE * DM * 2);
    short* b1b  = (short*)alloc((size_t)NE * 2 * DM * 2);
    short* b2b  = (short*)alloc((size_t)NE * DM * 2);
    short* gb   = (short*)alloc((size_t)NE * DM * 2);
    short* bb   = (short*)alloc((size_t)NE * DM * 2);
    short* w1b  = (short*)alloc((size_t)NE * 2 * DM * DM * 2);
    short* w2b  = (short*)alloc((size_t)NE * 2 * DM * DM * 2);
    short* xb   = (short*)alloc((size_t)NT * DM * 2);
    const size_t fixed = off;

    int Mc = NT;                                     // token chunk
    while (Mc > 512 && fixed + (size_t)Mc * 8192 > ws_size) Mc >>= 1;
    short* h = (short*)alloc((size_t)Mc * 2 * DM * 2);
    float* z = (float*)alloc((size_t)Mc * DM * sizeof(float));

    detect_kernel<<<1, 256, 0, stream>>>((const unsigned int*)d_in[0], flag);

    auto cvt = [&](const void* src, short* dst, size_t n) {
        int blocks = (int)((n / 4 + 255) / 256);
        if (blocks > 2048) blocks = 2048;
        convert_kernel<<<blocks, 256, 0, stream>>>(src, dst, (int)n, flag);
    };
    cvt(d_in[0], xb,  (size_t)NT * DM);
    cvt(d_in[1], gwb, (size_t)NE * DM);
    cvt(d_in[2], w1b, (size_t)NE * 2 * DM * DM);
    cvt(d_in[3], b1b, (size_t)NE * 2 * DM);
    cvt(d_in[4], w2b, (size_t)NE * 2 * DM * DM);
    cvt(d_in[5], b2b, (size_t)NE * DM);
    cvt(d_in[6], gb,  (size_t)NE * DM);
    cvt(d_in[7], bb,  (size_t)NE * DM);

    gate_kernel<<<NT / 4, 256, 0, stream>>>(d_in[0], d_in[1], comb, flag);

    for (int e = 0; e < NE; ++e) {
        const short* w1e = w1b + (size_t)e * 2 * DM * DM;
        const short* w2e = w2b + (size_t)e * 2 * DM * DM;
        const __hip_bfloat16* b1e = (const __hip_bfloat16*)(b1b + (size_t)e * 2 * DM);
        const __hip_bfloat16* b2e = (const __hip_bfloat16*)(b2b + (size_t)e * DM);
        const __hip_bfloat16* ge  = (const __hip_bfloat16*)(gb + (size_t)e * DM);
        const __hip_bfloat16* be  = (const __hip_bfloat16*)(bb + (size_t)e * DM);

        for (int c0 = 0; c0 < NT; c0 += Mc) {
            const short* xc = xb + (size_t)c0 * DM;

            dim3 g1(2 * DM / 128, Mc / 128);   // h = gelu(x @ w1e^T + b1e)
            gemm_bt<0><<<g1, 256, 0, stream>>>(xc, w1e, b1e, nullptr,
                                               (void*)h, Mc, 2 * DM, DM);

            dim3 g2(DM / 128, Mc / 128);       // z = x + h @ w2e^T + b2e
            gemm_bt<1><<<g2, 256, 0, stream>>>(h, w2e, b2e,
                                               (const __hip_bfloat16*)xc,
                                               (void*)z, Mc, DM, 2 * DM);

            ln_kernel<<<Mc / 4, 256, 0, stream>>>(z, comb, ge, be, d_out,
                                                  e, e > 0, c0, flag);
        }
    }
}